// Round 3
// baseline (434.350 us; speedup 1.0000x reference)
//
#include <hip/hip_runtime.h>
#include <stdint.h>

typedef __attribute__((ext_vector_type(8))) short short8;
typedef __attribute__((ext_vector_type(4))) float floatx4;

__device__ inline unsigned short f2bf(float f) {
    unsigned int u = __float_as_uint(f);
    u += 0x7fffu + ((u >> 16) & 1u);   // round-to-nearest-even
    return (unsigned short)(u >> 16);
}

// ---------------------------------------------------------------------------
// Tile worker: average over E experts + transpose + fp32->bf16.
// ---------------------------------------------------------------------------
__device__ void avg_transpose_tile(const float* __restrict__ src,
                                   unsigned short* __restrict__ dst,
                                   int E, int K, int Nsrc, int Ndst, int ldb,
                                   float scale, int tile_x, int tile_y) {
    __shared__ float tile[32][33];
    const int tid = threadIdx.x;
    const int tx = tid & 31;
    const int ty = tid >> 5;   // 0..7
    const int kb = tile_x * 32;
    const int nb = tile_y * 32;
#pragma unroll
    for (int p = 0; p < 4; ++p) {
        int kl = ty + p * 8;
        int k = kb + kl;
        int n = nb + tx;
        float s = 0.f;
        if (k < K && n < Nsrc) {
            for (int e = 0; e < E; ++e)
                s += src[(size_t)e * K * Nsrc + (size_t)k * Nsrc + n];
        }
        tile[kl][tx] = s * scale;
    }
    __syncthreads();
#pragma unroll
    for (int p = 0; p < 4; ++p) {
        int nl = ty + p * 8;
        int n = nb + nl;
        int k = kb + tx;
        if (n < Ndst && k < K)
            dst[(size_t)n * ldb + k] = f2bf(tile[tx][nl]);
    }
}

// ---------------------------------------------------------------------------
// One fused prep kernel: weight transforms + bias means + x0 pack + stats 0.
// ---------------------------------------------------------------------------
__global__ __launch_bounds__(256) void prep(
    const float* __restrict__ pW0, const float* __restrict__ pW1,
    const float* __restrict__ pWib, const float* __restrict__ rw1,
    const float* __restrict__ rw2, const float* __restrict__ pb0,
    const float* __restrict__ pb1, const float* __restrict__ pbib,
    const float* __restrict__ x0,
    unsigned short* __restrict__ Wmt, unsigned short* __restrict__ rw1t,
    unsigned short* __restrict__ rw2t, float* __restrict__ bm0,
    float* __restrict__ bm1, float* __restrict__ bm2,
    float* __restrict__ stats_zero, unsigned short* __restrict__ X0b) {
    int id = blockIdx.x;
    int tid = threadIdx.x;
    if (id < 1536) {
        avg_transpose_tile(pW0, Wmt + 0, 7, 1024, 1536, 1536, 2816, 1.f / 7.f,
                           id % 32, id / 32);
    } else if (id < 2688) {
        int t = id - 1536;
        avg_transpose_tile(pW1, Wmt + 1024, 7, 768, 1536, 1536, 2816, 1.f / 7.f,
                           t % 24, t / 24);
    } else if (id < 4224) {
        int t = id - 2688;
        avg_transpose_tile(pWib, Wmt + 1792, 7, 1024, 1536, 1536, 2816,
                           1.f / 7.f, t % 32, t / 32);
    } else if (id < 4736) {
        int t = id - 4224;
        avg_transpose_tile(rw1, rw1t, 1, 1024, 512, 512, 1024, 1.f, t % 32,
                           t / 32);
    } else if (id < 4800) {
        int t = id - 4736;
        avg_transpose_tile(rw2, rw2t, 1, 512, 100, 128, 512, 1.f, t % 16,
                           t / 16);
    } else if (id < 4806) {
        int i = (id - 4800) * 256 + tid;
        if (i < 1536) {
            float s0 = 0.f, s1 = 0.f, s2 = 0.f;
            for (int e = 0; e < 7; ++e) {
                s0 += pb0[e * 1536 + i];
                s1 += pb1[e * 1536 + i];
                s2 += pbib[e * 1536 + i];
            }
            const float inv = 1.f / 7.f;
            bm0[i] = s0 * inv; bm1[i] = s1 * inv; bm2[i] = s2 * inv;
        }
    } else if (id < 4807) {
        for (int i = tid; i < 1280; i += 256) stats_zero[i] = 0.f;
    } else {
        int base = (id - 4807) * 1024;  // vec4 index base; 2048 blocks
#pragma unroll
        for (int k = 0; k < 4; ++k) {
            int i = base + k * 256 + tid;
            float4 v = ((const float4*)x0)[i];
            ushort4 o;
            o.x = f2bf(v.x); o.y = f2bf(v.y); o.z = f2bf(v.z); o.w = f2bf(v.w);
            ((ushort4*)X0b)[i] = o;
        }
    }
}

// ---------------------------------------------------------------------------
// bf16 MFMA GEMM, m97 structure (router GEMMs): 128x128 tile, BK=32.
// C = A*B + bias[n], plus per-column atomic sum/sumsq (BN stats)
// ---------------------------------------------------------------------------
template <int MODE>
__global__ __launch_bounds__(256) void gemm_bt(
    const unsigned short* __restrict__ A, const unsigned short* __restrict__ Bt,
    float* __restrict__ C, int K, int Nreal, int ldc,
    const float* __restrict__ bias, float* __restrict__ sum,
    float* __restrict__ sumsq) {
    __shared__ __align__(16) unsigned short As[128 * 32];
    __shared__ __align__(16) unsigned short Bs[128 * 32];
    const int tid = threadIdx.x;
    const int lane = tid & 63;
    const int wv = tid >> 6;
    const int bm_off = blockIdx.x * 128;
    const int bn_off = blockIdx.y * 128;
    const int wm = (wv & 1) * 64;
    const int wn = (wv >> 1) * 64;
    floatx4 acc[4][4];
#pragma unroll
    for (int i = 0; i < 4; ++i)
#pragma unroll
        for (int j = 0; j < 4; ++j) acc[i][j] = (floatx4){0.f, 0.f, 0.f, 0.f};

    const int quad = lane >> 4;
    const int lrow = lane & 15;
    const int srow = lane >> 2;
    const int scol = (lane & 3) * 8;

    const unsigned short* Ag = A + (size_t)bm_off * K;
    const unsigned short* Bg = Bt + (size_t)bn_off * K;

    for (int k0 = 0; k0 < K; k0 += 32) {
#pragma unroll
        for (int r = 0; r < 2; ++r) {
            int chunk = r * 4 + wv;
            {
                const unsigned short* gp =
                    Ag + (size_t)(chunk * 16 + srow) * K + (k0 + scol);
                __builtin_amdgcn_global_load_lds(
                    (const __attribute__((address_space(1))) void*)gp,
                    (__attribute__((address_space(3))) void*)(As + chunk * 512),
                    16, 0, 0);
            }
            {
                const unsigned short* gp =
                    Bg + (size_t)(chunk * 16 + srow) * K + (k0 + scol);
                __builtin_amdgcn_global_load_lds(
                    (const __attribute__((address_space(1))) void*)gp,
                    (__attribute__((address_space(3))) void*)(Bs + chunk * 512),
                    16, 0, 0);
            }
        }
        __syncthreads();
        short8 af[4], bfr[4];
#pragma unroll
        for (int i = 0; i < 4; ++i)
            af[i] = *(const short8*)(As + (wm + i * 16 + lrow) * 32 + quad * 8);
#pragma unroll
        for (int j = 0; j < 4; ++j)
            bfr[j] = *(const short8*)(Bs + (wn + j * 16 + lrow) * 32 + quad * 8);
#pragma unroll
        for (int i = 0; i < 4; ++i)
#pragma unroll
            for (int j = 0; j < 4; ++j)
                acc[i][j] = __builtin_amdgcn_mfma_f32_16x16x32_bf16(
                    af[i], bfr[j], acc[i][j], 0, 0, 0);
        __syncthreads();
    }

    {
#pragma unroll
        for (int j = 0; j < 4; ++j) {
            int n = bn_off + wn + j * 16 + lrow;
            bool nok = (n < Nreal);
            float bv = nok ? bias[n] : 0.f;
            float s = 0.f, ss = 0.f;
#pragma unroll
            for (int i = 0; i < 4; ++i) {
#pragma unroll
                for (int r = 0; r < 4; ++r) {
                    float v = acc[i][j][r] + bv;
                    int m = bm_off + wm + i * 16 + quad * 4 + r;
                    if (nok) C[(size_t)m * ldc + n] = v;
                    s += v; ss += v * v;
                }
            }
            s += __shfl_xor(s, 16); s += __shfl_xor(s, 32);
            ss += __shfl_xor(ss, 16); ss += __shfl_xor(ss, 32);
            if (quad == 0 && nok) {
                atomicAdd(&sum[n], s);
                atomicAdd(&sumsq[n], ss);
            }
        }
    }
}

// ---------------------------------------------------------------------------
// 8-phase-style 256x256 deep-pipelined bf16 GEMM (m201 template port).
// BK=64, 512 thr = 8 waves (2M x 4N), per-wave 128x64 -> acc[8][4].
// LDS: A 4 half-slots [128][64] + B 4 half-slots = 128 KiB.  Slot period =
// 2 K-tiles.  Per tile: 4 phases x {ds_read subtile; stage; barrier;
// lgkmcnt(0); setprio; 16 MFMA; setprio; barrier}.  Stage 2 TILES ahead:
// B(t+2) at p2 (B slots free after p1), A(t+2) at p3 (A slots free after
// p2).  ONE counted vmcnt(8) per tile (tile t+2's 8 loads stay in flight;
// never drains until t=42).  XOR slot swizzle s^(row&7) on 8x16B slots ->
// conflict-free ds_read_b128; inverse swizzle pre-applied on global source
// (linear global_load_lds dest).  A split in 3 K-segments (A0 unscaled
// 1024 | A1 w1-scaled 768 | A2 w2-scaled 1024); acc *= w0[m] after tile 15.
// Grid (32, 6) = 192 blocks; XCD k owns M-slabs 4k..4k+3 x all N panels.
// C = w0*A0part + A1part + A2part + w0*g0 + w1*g1 + w2*g2 per (m,n).
// ---------------------------------------------------------------------------
__global__ __launch_bounds__(512, 2) void gemm256(
    const unsigned short* __restrict__ A0, const unsigned short* __restrict__ A1,
    const unsigned short* __restrict__ A2, const unsigned short* __restrict__ Bt,
    float* __restrict__ C, int ldc,
    const float* __restrict__ w0, const float* __restrict__ w1,
    const float* __restrict__ w2, const float* __restrict__ g0,
    const float* __restrict__ g1, const float* __restrict__ g2) {
    __shared__ __align__(16) unsigned short lds[65536];  // A: 4x8192, B: +32768

    const int tid = threadIdx.x;
    const int lane = tid & 63;
    const int wv = tid >> 6;          // 0..7
    const int wm = wv >> 2;           // 0..1  (M half)
    const int wn = wv & 3;            // 0..3  (N quarter)
    const int quad = lane >> 4;
    const int lrow = lane & 15;

    int id = blockIdx.y * 32 + blockIdx.x;  // 0..191
    const int xcd = id & 7;
    const int loc = id >> 3;                // 0..23
    const int row0 = (xcd * 4 + (loc & 3)) * 256;
    const int col0 = (loc >> 2) * 256;

    // staging: thread covers 16B chunk p = c*512+tid of a [128][64] half.
    // dest linear; global source col-slot = physslot ^ (row&7)  (involution)
    const int rr = tid >> 3;              // row within 64-row chunk
    const int sl = (tid & 7) ^ (rr & 7);  // logical slot fetched
    // read side: logical slot s of row r lives at phys slot s^(r&7)
    const int sxor = lrow & 7;
    const int brow = (wn & 1) * 64;       // wave's row base within B half

    auto stA = [&](int kt, int mh) {
        int slot = ((kt << 1) + mh) & 3;
        const unsigned short* base;
        int lda, koff;
        if (kt < 16)      { base = A0; lda = 1024; koff = kt << 6; }
        else if (kt < 28) { base = A1; lda = 768;  koff = (kt - 16) << 6; }
        else              { base = A2; lda = 1024; koff = (kt - 28) << 6; }
        const unsigned short* gp =
            base + (size_t)(row0 + mh * 128 + rr) * lda + koff + sl * 8;
        unsigned short* d = (unsigned short*)lds + slot * 8192 + wv * 512;
        __builtin_amdgcn_global_load_lds(
            (const __attribute__((address_space(1))) void*)gp,
            (__attribute__((address_space(3))) void*)d, 16, 0, 0);
        __builtin_amdgcn_global_load_lds(
            (const __attribute__((address_space(1))) void*)(gp + (size_t)64 * lda),
            (__attribute__((address_space(3))) void*)(d + 4096), 16, 0, 0);
    };
    auto stB = [&](int kt, int nh) {
        int slot = ((kt << 1) + nh) & 3;
        const unsigned short* gp =
            Bt + (size_t)(col0 + nh * 128 + rr) * 2816 + (kt << 6) + sl * 8;
        unsigned short* d = (unsigned short*)lds + 32768 + slot * 8192 + wv * 512;
        __builtin_amdgcn_global_load_lds(
            (const __attribute__((address_space(1))) void*)gp,
            (__attribute__((address_space(3))) void*)d, 16, 0, 0);
        __builtin_amdgcn_global_load_lds(
            (const __attribute__((address_space(1))) void*)(gp + (size_t)64 * 2816),
            (__attribute__((address_space(3))) void*)(d + 4096), 16, 0, 0);
    };

#define LDA_FRAG(i, h) \
    (*(const short8*)(Ar + ((i) * 16 + lrow) * 64 + ((((h) << 2) + quad) ^ sxor) * 8))
#define LDB_FRAG(j, h) \
    (*(const short8*)(Br + (brow + (j) * 16 + lrow) * 64 + ((((h) << 2) + quad) ^ sxor) * 8))
#define MFMA_(d, a, b) \
    d = __builtin_amdgcn_mfma_f32_16x16x32_bf16(a, b, d, 0, 0, 0)
#define PRE_MFMA                                            \
    asm volatile("s_barrier" ::: "memory");                 \
    asm volatile("s_waitcnt lgkmcnt(0)" ::: "memory");      \
    __builtin_amdgcn_sched_barrier(0);                      \
    __builtin_amdgcn_s_setprio(1);
#define POST_MFMA                                           \
    __builtin_amdgcn_s_setprio(0);                          \
    __builtin_amdgcn_sched_barrier(0);                      \
    asm volatile("s_barrier" ::: "memory");

    floatx4 acc[8][4];
#pragma unroll
    for (int i = 0; i < 8; ++i)
#pragma unroll
        for (int j = 0; j < 4; ++j) acc[i][j] = (floatx4){0.f, 0.f, 0.f, 0.f};

    const int NT = 44;  // 2816 / 64
    // prologue: stage tiles 0 and 1 (8 + 8 loads)
    stA(0, 0); stA(0, 1); stB(0, 0); stB(0, 1);
    stA(1, 0); stA(1, 1); stB(1, 0); stB(1, 1);
    asm volatile("s_waitcnt vmcnt(8)" ::: "memory");  // tile 0 landed
    asm volatile("s_barrier" ::: "memory");

    short8 af[4][2], bf0[2][2], bf1[2][2];
#pragma unroll 2
    for (int t = 0; t < NT; ++t) {
        const int pb = (t & 1) << 1;
        const unsigned short* Ar = (const unsigned short*)lds + (pb + wm) * 8192;
        const unsigned short* Br =
            (const unsigned short*)lds + 32768 + (pb + (wn >> 1)) * 8192;

        // ---- phase 0: read A-lo frags (8) + B-lo frags (4); MFMA Q00
#pragma unroll
        for (int i = 0; i < 4; ++i) {
            af[i][0] = LDA_FRAG(i, 0); af[i][1] = LDA_FRAG(i, 1);
        }
#pragma unroll
        for (int j = 0; j < 2; ++j) {
            bf0[j][0] = LDB_FRAG(j, 0); bf0[j][1] = LDB_FRAG(j, 1);
        }
        PRE_MFMA
#pragma unroll
        for (int h = 0; h < 2; ++h)
#pragma unroll
            for (int i = 0; i < 4; ++i)
#pragma unroll
                for (int j = 0; j < 2; ++j)
                    MFMA_(acc[i][j], af[i][h], bf0[j][h]);
        POST_MFMA

        // ---- phase 1: read B-hi frags (4); MFMA Q01
#pragma unroll
        for (int j = 0; j < 2; ++j) {
            bf1[j][0] = LDB_FRAG(2 + j, 0); bf1[j][1] = LDB_FRAG(2 + j, 1);
        }
        PRE_MFMA
#pragma unroll
        for (int h = 0; h < 2; ++h)
#pragma unroll
            for (int i = 0; i < 4; ++i)
#pragma unroll
                for (int j = 0; j < 2; ++j)
                    MFMA_(acc[i][2 + j], af[i][h], bf1[j][h]);
        POST_MFMA

        // ---- phase 2: read A-hi frags (8); stage B(t+2); MFMA Q10
#pragma unroll
        for (int i = 0; i < 4; ++i) {
            af[i][0] = LDA_FRAG(4 + i, 0); af[i][1] = LDA_FRAG(4 + i, 1);
        }
        if (t + 2 < NT) { stB(t + 2, 0); stB(t + 2, 1); }
        PRE_MFMA
#pragma unroll
        for (int h = 0; h < 2; ++h)
#pragma unroll
            for (int i = 0; i < 4; ++i)
#pragma unroll
                for (int j = 0; j < 2; ++j)
                    MFMA_(acc[4 + i][j], af[i][h], bf0[j][h]);
        POST_MFMA

        // ---- phase 3: stage A(t+2); MFMA Q11; counted vmcnt + barrier
        if (t + 2 < NT) { stA(t + 2, 0); stA(t + 2, 1); }
        asm volatile("s_barrier" ::: "memory");
        asm volatile("s_waitcnt lgkmcnt(0)" ::: "memory");
        __builtin_amdgcn_sched_barrier(0);
        __builtin_amdgcn_s_setprio(1);
#pragma unroll
        for (int h = 0; h < 2; ++h)
#pragma unroll
            for (int i = 0; i < 4; ++i)
#pragma unroll
                for (int j = 0; j < 2; ++j)
                    MFMA_(acc[4 + i][2 + j], af[i][h], bf1[j][h]);
        __builtin_amdgcn_s_setprio(0);
        __builtin_amdgcn_sched_barrier(0);
        if (t < NT - 2)
            asm volatile("s_waitcnt vmcnt(8)" ::: "memory");  // t+1 landed
        else if (t == NT - 2)
            asm volatile("s_waitcnt vmcnt(0)" ::: "memory");  // drain for last
        asm volatile("s_barrier" ::: "memory");

        // ---- segment-0 boundary (K=1024): fold router weight w0[m]
        if (t == 15) {
#pragma unroll
            for (int ii = 0; ii < 8; ++ii)
#pragma unroll
                for (int r = 0; r < 4; ++r) {
                    float f = w0[row0 + wm * 128 + ii * 16 + quad * 4 + r];
#pragma unroll
                    for (int j = 0; j < 4; ++j) acc[ii][j][r] *= f;
                }
        }
    }

    // ---- epilogue: weighted-bias add + store
#pragma unroll
    for (int i = 0; i < 8; ++i) {
#pragma unroll
        for (int r = 0; r < 4; ++r) {
            int m = row0 + wm * 128 + i * 16 + quad * 4 + r;
            float a0 = w0[m], a1 = w1[m], a2 = w2[m];
#pragma unroll
            for (int j = 0; j < 4; ++j) {
                int n = col0 + wn * 64 + j * 16 + lrow;
                C[(size_t)m * ldc + n] =
                    acc[i][j][r] + a0 * g0[n] + a1 * g1[n] + a2 * g2[n];
            }
        }
    }
#undef LDA_FRAG
#undef LDB_FRAG
#undef MFMA_
#undef PRE_MFMA
#undef POST_MFMA
}

// BN1 final + relu + bf16 pack.  h1 [8192,512].
__global__ __launch_bounds__(256) void bn_relu_pack(
    const float* __restrict__ h, unsigned short* __restrict__ out,
    const float* __restrict__ sum, const float* __restrict__ sumsq,
    const float* __restrict__ g, const float* __restrict__ b) {
    __shared__ float sc[512], sh[512];
    const float invB = 1.f / 8192.f;
    for (int c = threadIdx.x; c < 512; c += 256) {
        float m = sum[c] * invB;
        float v = sumsq[c] * invB - m * m;
        float s = g[c] * rsqrtf(v + 1e-5f);
        sc[c] = s;
        sh[c] = b[c] - m * s;
    }
    __syncthreads();
    int base = blockIdx.x * 4096;
#pragma unroll
    for (int k = 0; k < 16; ++k) {
        int i = base + k * 256 + threadIdx.x;
        int c4 = (i & 127) * 4;
        float4 v = ((const float4*)h)[i];
        ushort4 o;
        o.x = f2bf(fmaxf(v.x * sc[c4 + 0] + sh[c4 + 0], 0.f));
        o.y = f2bf(fmaxf(v.y * sc[c4 + 1] + sh[c4 + 1], 0.f));
        o.z = f2bf(fmaxf(v.z * sc[c4 + 2] + sh[c4 + 2], 0.f));
        o.w = f2bf(fmaxf(v.w * sc[c4 + 3] + sh[c4 + 3], 0.f));
        ((ushort4*)out)[i] = o;
    }
}

// BN2 final + tanh + [100x3] GEMM + sigmoid + softmax.
__global__ __launch_bounds__(128) void router_tail(
    const float* __restrict__ h2, const float* __restrict__ sum,
    const float* __restrict__ sumsq, const float* __restrict__ g,
    const float* __restrict__ b, const float* __restrict__ rw3,
    const float* __restrict__ rb3, float* __restrict__ w0,
    float* __restrict__ w1, float* __restrict__ w2) {
    __shared__ float sc[100], sh[100], w3[300], b3[3];
    int tid = threadIdx.x;
    const float invB = 1.f / 8192.f;
    if (tid < 100) {
        float m = sum[tid] * invB;
        float v = sumsq[tid] * invB - m * m;
        float s = g[tid] * rsqrtf(v + 1e-5f);
        sc[tid] = s;
        sh[tid] = b[tid] - m * s;
    }
    for (int i = tid; i < 300; i += 128) w3[i] = rw3[i];
    if (tid < 3) b3[tid] = rb3[tid];
    __syncthreads();
    int bi = blockIdx.x * 128 + tid;
    float l0 = b3[0], l1 = b3[1], l2 = b3[2];
    const float* hr = h2 + (size_t)bi * 100;
    for (int k = 0; k < 100; ++k) {
        float t = tanhf(hr[k] * sc[k] + sh[k]);
        l0 += t * w3[k * 3 + 0];
        l1 += t * w3[k * 3 + 1];
        l2 += t * w3[k * 3 + 2];
    }
    l0 = 1.f / (1.f + expf(-l0));
    l1 = 1.f / (1.f + expf(-l1));
    l2 = 1.f / (1.f + expf(-l2));
    float mx = fmaxf(l0, fmaxf(l1, l2));
    float e0 = expf(l0 - mx), e1 = expf(l1 - mx), e2 = expf(l2 - mx);
    float inv = 1.f / (e0 + e1 + e2);
    w0[bi] = e0 * inv; w1[bi] = e1 * inv; w2[bi] = e2 * inv;
}

// Pack w1*x1 -> X1b [8192,768] and w2*xib -> Xib [8192,1024] as bf16.
__global__ __launch_bounds__(256) void pack1ib(
    const float* __restrict__ x1, const float* __restrict__ xib,
    const float* __restrict__ w1, const float* __restrict__ w2,
    unsigned short* __restrict__ X1b, unsigned short* __restrict__ Xib) {
    int i0 = blockIdx.x * 1024 + threadIdx.x;
#pragma unroll
    for (int k = 0; k < 4; ++k) {
        int i = i0 + k * 256;
        int b = i / 448;
        int g = i % 448;
        float w;
        const float* src;
        unsigned short* dst;
        if (g < 192) {
            w = w1[b];
            src = x1 + (size_t)b * 768 + g * 4;
            dst = X1b + (size_t)b * 768 + g * 4;
        } else {
            w = w2[b];
            src = xib + (size_t)b * 1024 + (g - 192) * 4;
            dst = Xib + (size_t)b * 1024 + (g - 192) * 4;
        }
        float4 v = *(const float4*)src;
        ushort4 o;
        o.x = f2bf(v.x * w); o.y = f2bf(v.y * w);
        o.z = f2bf(v.z * w); o.w = f2bf(v.w * w);
        *(ushort4*)dst = o;
    }
}

// per-row L2 normalization in place, one wave per row (1536 cols)
__global__ __launch_bounds__(256) void l2norm_rows(float* __restrict__ out) {
    int wv = threadIdx.x >> 6;
    int lane = threadIdx.x & 63;
    int row = blockIdx.x * 4 + wv;
    float4* rp = (float4*)(out + (size_t)row * 1536);
    float4 v[6];
    float ss = 0.f;
#pragma unroll
    for (int t = 0; t < 6; ++t) {
        v[t] = rp[lane + t * 64];
        ss += v[t].x * v[t].x + v[t].y * v[t].y + v[t].z * v[t].z + v[t].w * v[t].w;
    }
#pragma unroll
    for (int o = 32; o > 0; o >>= 1) ss += __shfl_xor(ss, o);
    float inv = 1.f / fmaxf(sqrtf(ss), 1e-12f);
#pragma unroll
    for (int t = 0; t < 6; ++t) {
        v[t].x *= inv; v[t].y *= inv; v[t].z *= inv; v[t].w *= inv;
        rp[lane + t * 64] = v[t];
    }
}

extern "C" void kernel_launch(void* const* d_in, const int* in_sizes, int n_in,
                              void* d_out, int out_size, void* d_ws,
                              size_t ws_size, hipStream_t stream) {
    (void)in_sizes; (void)n_in; (void)out_size; (void)ws_size;
    const float* x0   = (const float*)d_in[0];
    const float* x1   = (const float*)d_in[1];
    const float* xib  = (const float*)d_in[2];
    const float* pW0  = (const float*)d_in[3];
    const float* pb0  = (const float*)d_in[4];
    const float* pW1  = (const float*)d_in[5];
    const float* pb1  = (const float*)d_in[6];
    const float* pWib = (const float*)d_in[7];
    const float* pbib = (const float*)d_in[8];
    const float* rw1  = (const float*)d_in[9];
    const float* rb1  = (const float*)d_in[10];
    const float* rg1  = (const float*)d_in[11];
    const float* rbt1 = (const float*)d_in[12];
    const float* rw2  = (const float*)d_in[13];
    const float* rb2  = (const float*)d_in[14];
    const float* rg2  = (const float*)d_in[15];
    const float* rbt2 = (const float*)d_in[16];
    const float* rw3  = (const float*)d_in[17];
    const float* rb3  = (const float*)d_in[18];
    float* out = (float*)d_out;

    char* ws = (char*)d_ws;
    // --- workspace layout (~53.5 MB, with temporal aliasing) ---
    unsigned short* Wmt = (unsigned short*)(ws);  // [1536, 2816] bf16
    char* stats = ws + 8650752;
    float* sum1   = (float*)(stats + 0);      // 512 f
    float* sumsq1 = (float*)(stats + 2048);   // 512 f
    float* sum2   = (float*)(stats + 4096);   // 128 f
    float* sumsq2 = (float*)(stats + 4608);   // 128 f  (zero region = 1280 f)
    float* bm0    = (float*)(stats + 10240);
    float* bm1    = (float*)(stats + 16384);
    float* bm2    = (float*)(stats + 22528);
    float* w0p    = (float*)(stats + 28672);
    float* w1p    = (float*)(stats + 61440);
    float* w2p    = (float*)(stats + 94208);
    unsigned short* rw1t = (unsigned short*)(ws + 8781824);   // [512,1024] bf16
    unsigned short* rw2t = (unsigned short*)(ws + 9830400);   // [128,512] bf16
    char* R5 = ws + 9961472;
    unsigned short* X0b = (unsigned short*)(R5);              // [8192,1024] bf16
    float* h1           = (float*)(R5 + 16777216);            // [8192,512] f32
    unsigned short* h1n = (unsigned short*)(R5 + 33554432);   // [8192,512] bf16
    float* h2           = (float*)(R5 + 41943040);            // [8192,100] f32
    unsigned short* X1b = (unsigned short*)(R5 + 16777216);   // [8192,768] bf16
    unsigned short* Xib = (unsigned short*)(R5 + 29360128);   // [8192,1024] bf16

    // 1. fused prep
    prep<<<6855, 256, 0, stream>>>(pW0, pW1, pWib, rw1, rw2, pb0, pb1, pbib, x0,
                                   Wmt, rw1t, rw2t, bm0, bm1, bm2,
                                   (float*)stats, X0b);
    // 2. router GEMM1 (fused BN stats)
    gemm_bt<2><<<dim3(64, 4), 256, 0, stream>>>(
        X0b, rw1t, h1, 1024, 512, 512, rb1, sum1, sumsq1);
    // 3. BN1 apply + relu + bf16 pack
    bn_relu_pack<<<256, 256, 0, stream>>>(h1, h1n, sum1, sumsq1, rg1, rbt1);
    // 4. router GEMM2 (fused BN stats)
    gemm_bt<2><<<dim3(64, 1), 256, 0, stream>>>(
        h1n, rw2t, h2, 512, 100, 100, rb2, sum2, sumsq2);
    // 5. router tail -> weights
    router_tail<<<64, 128, 0, stream>>>(h2, sum2, sumsq2, rg2, rbt2, rw3, rb3,
                                        w0p, w1p, w2p);
    // 6. pack scaled x1/xib segments
    pack1ib<<<3584, 256, 0, stream>>>(x1, xib, w1p, w2p, X1b, Xib);
    // 7. big GEMM, 8-phase 256x256 pipeline
    gemm256<<<dim3(32, 6), 512, 0, stream>>>(X0b, X1b, Xib, Wmt, out, 1536,
                                             w0p, w1p, w2p, bm0, bm1, bm2);
    // 8. per-row L2 normalize
    l2norm_rows<<<2048, 256, 0, stream>>>(out);
}

// Round 7
// 416.000 us; speedup vs baseline: 1.0441x; 1.0441x over previous
//
#include <hip/hip_runtime.h>
#include <stdint.h>

typedef __attribute__((ext_vector_type(8))) short short8;
typedef __attribute__((ext_vector_type(4))) float floatx4;

__device__ inline unsigned short f2bf(float f) {
    unsigned int u = __float_as_uint(f);
    u += 0x7fffu + ((u >> 16) & 1u);   // round-to-nearest-even
    return (unsigned short)(u >> 16);
}

// ---------------------------------------------------------------------------
// Tile worker: average over E experts + transpose + fp32->bf16.
// src[e, k, n] row-major; dst[n, k] bf16, leading dim ldb.
// Rows n in [Nsrc, Ndst) zero-filled (pads rw2 N=100 -> 128).
// ---------------------------------------------------------------------------
__device__ void avg_transpose_tile(const float* __restrict__ src,
                                   unsigned short* __restrict__ dst,
                                   int E, int K, int Nsrc, int Ndst, int ldb,
                                   float scale, int tile_x, int tile_y) {
    __shared__ float tile[32][33];
    const int tid = threadIdx.x;
    const int tx = tid & 31;
    const int ty = tid >> 5;   // 0..7
    const int kb = tile_x * 32;
    const int nb = tile_y * 32;
#pragma unroll
    for (int p = 0; p < 4; ++p) {
        int kl = ty + p * 8;
        int k = kb + kl;
        int n = nb + tx;
        float s = 0.f;
        if (k < K && n < Nsrc) {
            for (int e = 0; e < E; ++e)
                s += src[(size_t)e * K * Nsrc + (size_t)k * Nsrc + n];
        }
        tile[kl][tx] = s * scale;
    }
    __syncthreads();
#pragma unroll
    for (int p = 0; p < 4; ++p) {
        int nl = ty + p * 8;
        int n = nb + nl;
        int k = kb + tx;
        if (n < Ndst && k < K)
            dst[(size_t)n * ldb + k] = f2bf(tile[tx][nl]);
    }
}

// ---------------------------------------------------------------------------
// One fused prep kernel: weight transforms + bias means + x0 pack + stats 0.
// ---------------------------------------------------------------------------
__global__ __launch_bounds__(256) void prep(
    const float* __restrict__ pW0, const float* __restrict__ pW1,
    const float* __restrict__ pWib, const float* __restrict__ rw1,
    const float* __restrict__ rw2, const float* __restrict__ pb0,
    const float* __restrict__ pb1, const float* __restrict__ pbib,
    const float* __restrict__ x0,
    unsigned short* __restrict__ Wmt, unsigned short* __restrict__ rw1t,
    unsigned short* __restrict__ rw2t, float* __restrict__ bm0,
    float* __restrict__ bm1, float* __restrict__ bm2,
    float* __restrict__ stats_zero, unsigned short* __restrict__ X0b) {
    int id = blockIdx.x;
    int tid = threadIdx.x;
    if (id < 1536) {
        avg_transpose_tile(pW0, Wmt + 0, 7, 1024, 1536, 1536, 2816, 1.f / 7.f,
                           id % 32, id / 32);
    } else if (id < 2688) {
        int t = id - 1536;
        avg_transpose_tile(pW1, Wmt + 1024, 7, 768, 1536, 1536, 2816, 1.f / 7.f,
                           t % 24, t / 24);
    } else if (id < 4224) {
        int t = id - 2688;
        avg_transpose_tile(pWib, Wmt + 1792, 7, 1024, 1536, 1536, 2816,
                           1.f / 7.f, t % 32, t / 32);
    } else if (id < 4736) {
        int t = id - 4224;
        avg_transpose_tile(rw1, rw1t, 1, 1024, 512, 512, 1024, 1.f, t % 32,
                           t / 32);
    } else if (id < 4800) {
        int t = id - 4736;
        avg_transpose_tile(rw2, rw2t, 1, 512, 100, 128, 512, 1.f, t % 16,
                           t / 16);
    } else if (id < 4806) {
        int i = (id - 4800) * 256 + tid;
        if (i < 1536) {
            float s0 = 0.f, s1 = 0.f, s2 = 0.f;
            for (int e = 0; e < 7; ++e) {
                s0 += pb0[e * 1536 + i];
                s1 += pb1[e * 1536 + i];
                s2 += pbib[e * 1536 + i];
            }
            const float inv = 1.f / 7.f;
            bm0[i] = s0 * inv; bm1[i] = s1 * inv; bm2[i] = s2 * inv;
        }
    } else if (id < 4807) {
        for (int i = tid; i < 1280; i += 256) stats_zero[i] = 0.f;
    } else {
        int base = (id - 4807) * 1024;  // vec4 index base; 2048 blocks
#pragma unroll
        for (int k = 0; k < 4; ++k) {
            int i = base + k * 256 + tid;
            float4 v = ((const float4*)x0)[i];
            ushort4 o;
            o.x = f2bf(v.x); o.y = f2bf(v.y); o.z = f2bf(v.z); o.w = f2bf(v.w);
            ((ushort4*)X0b)[i] = o;
        }
    }
}

// ---------------------------------------------------------------------------
// bf16 MFMA GEMM, m97 structure (router GEMMs): 128x128 tile, BK=32.
// C = A*B + bias[n], plus per-column atomic sum/sumsq (BN stats)
// ---------------------------------------------------------------------------
template <int MODE>
__global__ __launch_bounds__(256) void gemm_bt(
    const unsigned short* __restrict__ A, const unsigned short* __restrict__ Bt,
    float* __restrict__ C, int K, int Nreal, int ldc,
    const float* __restrict__ bias, float* __restrict__ sum,
    float* __restrict__ sumsq) {
    __shared__ __align__(16) unsigned short As[128 * 32];
    __shared__ __align__(16) unsigned short Bs[128 * 32];
    const int tid = threadIdx.x;
    const int lane = tid & 63;
    const int wv = tid >> 6;
    const int bm_off = blockIdx.x * 128;
    const int bn_off = blockIdx.y * 128;
    const int wm = (wv & 1) * 64;
    const int wn = (wv >> 1) * 64;
    floatx4 acc[4][4];
#pragma unroll
    for (int i = 0; i < 4; ++i)
#pragma unroll
        for (int j = 0; j < 4; ++j) acc[i][j] = (floatx4){0.f, 0.f, 0.f, 0.f};

    const int quad = lane >> 4;
    const int lrow = lane & 15;
    const int srow = lane >> 2;
    const int scol = (lane & 3) * 8;

    const unsigned short* Ag = A + (size_t)bm_off * K;
    const unsigned short* Bg = Bt + (size_t)bn_off * K;

    for (int k0 = 0; k0 < K; k0 += 32) {
#pragma unroll
        for (int r = 0; r < 2; ++r) {
            int chunk = r * 4 + wv;
            {
                const unsigned short* gp =
                    Ag + (size_t)(chunk * 16 + srow) * K + (k0 + scol);
                __builtin_amdgcn_global_load_lds(
                    (const __attribute__((address_space(1))) void*)gp,
                    (__attribute__((address_space(3))) void*)(As + chunk * 512),
                    16, 0, 0);
            }
            {
                const unsigned short* gp =
                    Bg + (size_t)(chunk * 16 + srow) * K + (k0 + scol);
                __builtin_amdgcn_global_load_lds(
                    (const __attribute__((address_space(1))) void*)gp,
                    (__attribute__((address_space(3))) void*)(Bs + chunk * 512),
                    16, 0, 0);
            }
        }
        __syncthreads();
        short8 af[4], bfr[4];
#pragma unroll
        for (int i = 0; i < 4; ++i)
            af[i] = *(const short8*)(As + (wm + i * 16 + lrow) * 32 + quad * 8);
#pragma unroll
        for (int j = 0; j < 4; ++j)
            bfr[j] = *(const short8*)(Bs + (wn + j * 16 + lrow) * 32 + quad * 8);
#pragma unroll
        for (int i = 0; i < 4; ++i)
#pragma unroll
            for (int j = 0; j < 4; ++j)
                acc[i][j] = __builtin_amdgcn_mfma_f32_16x16x32_bf16(
                    af[i], bfr[j], acc[i][j], 0, 0, 0);
        __syncthreads();
    }

    {  // MODE 2 epilogue
#pragma unroll
        for (int j = 0; j < 4; ++j) {
            int n = bn_off + wn + j * 16 + lrow;
            bool nok = (n < Nreal);
            float bv = nok ? bias[n] : 0.f;
            float s = 0.f, ss = 0.f;
#pragma unroll
            for (int i = 0; i < 4; ++i) {
#pragma unroll
                for (int r = 0; r < 4; ++r) {
                    float v = acc[i][j][r] + bv;
                    int m = bm_off + wm + i * 16 + quad * 4 + r;
                    if (nok) C[(size_t)m * ldc + n] = v;
                    s += v; ss += v * v;
                }
            }
            s += __shfl_xor(s, 16); s += __shfl_xor(s, 32);
            ss += __shfl_xor(ss, 16); ss += __shfl_xor(ss, 32);
            if (quad == 0 && nok) {
                atomicAdd(&sum[n], s);
                atomicAdd(&sumsq[n], ss);
            }
        }
    }
}

// ---------------------------------------------------------------------------
// Deep-pipelined bf16 GEMM for the big combine (step 7).
// Tile 256(M) x 192(N), BK=32, 512 threads = 8 waves (2M x 4N), per-wave
// 128x48 -> acc[8][3].  Quadruple-buffered LDS (112 KiB), global_load_lds
// staging 3 tiles ahead, counted vmcnt at tile boundaries, raw s_barrier,
// XOR slot-swizzle, s_setprio around MFMA clusters.
// A is split into 3 K-segment buffers: A0 [8192,1024] UNSCALED (shared with
// router GEMM1), A1 [8192,768] pre-scaled by w1, A2 [8192,1024] pre-scaled
// by w2.  At the end of segment 0 (tile t==31) the accumulator is scaled by
// w0[m] (exact: out = w0*S0 + S1' + S2' + sum_k wk*bmk).
// XCD swizzle: XCD k owns M-tiles 4k..4k+3 x all 8 N-panels, so 8 concurrent
// blocks share each A slab in L2 (per-K-step working set ~112 KB/XCD).
// Grid (32, 8) = 256 blocks = 1 per CU.  K = 2816 fixed (tiles 32+24+32).
// ---------------------------------------------------------------------------
__global__ __launch_bounds__(512, 2) void gemm256(
    const unsigned short* __restrict__ A0, const unsigned short* __restrict__ A1,
    const unsigned short* __restrict__ A2, const unsigned short* __restrict__ Bt,
    float* __restrict__ C, int ldc,
    const float* __restrict__ w0, const float* __restrict__ w1,
    const float* __restrict__ w2, const float* __restrict__ g0,
    const float* __restrict__ g1, const float* __restrict__ g2) {
    // LDS: A 4 bufs x 256x32 bf16 (16 KiB each) + B 4 bufs x 192x32 (12 KiB)
    __shared__ __align__(16) unsigned short lds[57344];
    unsigned short* Asb = lds;            // buffer b at + b*8192 elems
    unsigned short* Bsb = lds + 32768;    // buffer b at + b*6144 elems

    const int tid = threadIdx.x;
    const int lane = tid & 63;
    const int wv = tid >> 6;          // 0..7
    const int wm = wv >> 2;           // 0..1  (M half)
    const int wn = wv & 3;            // 0..3  (N quarter)
    const int quad = lane >> 4;       // k-slot
    const int lrow = lane & 15;

    // XCD-swizzle: blocks round-robin to XCDs by b%8; XCD k -> M-slabs 4k..4k+3
    int b = blockIdx.y * 32 + blockIdx.x;
    const int xcd = b & 7;
    const int loc = b >> 3;           // 0..31
    const int row0 = (xcd * 4 + (loc & 3)) * 256;
    const int col0 = (loc >> 2) * 192;

    // ---- staging source offsets (swizzle pre-applied on the global side) ---
    // LDS physical layout per buffer: row-major [rows][32 bf16] with 16B-slot
    // swizzle  s_phys = s_log ^ ((row>>1)&3)   (involution).
    const int rA = tid >> 2;                       // 0..127 (c=0 rows)
    const int slA = (tid & 3) ^ ((rA >> 1) & 3);
    const size_t sA0 = (size_t)(row0 + rA) * 1024 + slA * 8;  // lda 1024 (A0/A2)
    const size_t sA1 = (size_t)(row0 + rA) * 768 + slA * 8;   // lda 768  (A1)

    size_t srcB16;
    {
        int r = tid >> 2;
        int sl = (tid & 3) ^ ((r >> 1) & 3);
        srcB16 = (size_t)(col0 + r) * 2816 + sl * 8;
    }
    size_t srcB4[2];
#pragma unroll
    for (int d = 0; d < 2; ++d) {
        int byteoff = d * 2048 + tid * 4;  // within B rows 128..191 region
        int r = 128 + (byteoff >> 6);
        int sl = ((byteoff >> 4) & 3) ^ ((r >> 1) & 3);
        srcB4[d] = (size_t)(col0 + r) * 2816 + sl * 8 + ((tid & 3) << 1);
    }

    auto stageA = [&](int kt, int buf) {
        unsigned short* d0 = Asb + buf * 8192 + wv * 512;
        if (kt < 32) {
            const unsigned short* g = A0 + (size_t)kt * 32;
            __builtin_amdgcn_global_load_lds(
                (const __attribute__((address_space(1))) void*)(g + sA0),
                (__attribute__((address_space(3))) void*)d0, 16, 0, 0);
            __builtin_amdgcn_global_load_lds(
                (const __attribute__((address_space(1))) void*)(g + sA0 + 128 * 1024),
                (__attribute__((address_space(3))) void*)(d0 + 4096), 16, 0, 0);
        } else if (kt < 56) {
            const unsigned short* g = A1 + (size_t)(kt - 32) * 32;
            __builtin_amdgcn_global_load_lds(
                (const __attribute__((address_space(1))) void*)(g + sA1),
                (__attribute__((address_space(3))) void*)d0, 16, 0, 0);
            __builtin_amdgcn_global_load_lds(
                (const __attribute__((address_space(1))) void*)(g + sA1 + 128 * 768),
                (__attribute__((address_space(3))) void*)(d0 + 4096), 16, 0, 0);
        } else {
            const unsigned short* g = A2 + (size_t)(kt - 56) * 32;
            __builtin_amdgcn_global_load_lds(
                (const __attribute__((address_space(1))) void*)(g + sA0),
                (__attribute__((address_space(3))) void*)d0, 16, 0, 0);
            __builtin_amdgcn_global_load_lds(
                (const __attribute__((address_space(1))) void*)(g + sA0 + 128 * 1024),
                (__attribute__((address_space(3))) void*)(d0 + 4096), 16, 0, 0);
        }
    };
    auto stageB = [&](int kt, int buf) {
        const size_t k0 = (size_t)kt * 32;
        __builtin_amdgcn_global_load_lds(
            (const __attribute__((address_space(1))) void*)(Bt + srcB16 + k0),
            (__attribute__((address_space(3))) void*)(Bsb + buf * 6144 +
                                                     wv * 512),
            16, 0, 0);
#pragma unroll
        for (int d = 0; d < 2; ++d) {
            __builtin_amdgcn_global_load_lds(
                (const __attribute__((address_space(1))) void*)(Bt + srcB4[d] + k0),
                (__attribute__((address_space(3))) void*)(Bsb + buf * 6144 +
                                                         4096 + d * 1024 +
                                                         wv * 128),
                4, 0, 0);
        }
    };

    floatx4 acc[8][3];
#pragma unroll
    for (int i = 0; i < 8; ++i)
#pragma unroll
        for (int j = 0; j < 3; ++j) acc[i][j] = (floatx4){0.f, 0.f, 0.f, 0.f};

    const int NT = 88;  // 2816 / 32
    // prologue: fill 3 buffers (5 loads each per wave)
    stageA(0, 0); stageB(0, 0);
    stageA(1, 1); stageB(1, 1);
    stageA(2, 2); stageB(2, 2);
    asm volatile("s_waitcnt vmcnt(10)" ::: "memory");  // tile 0 landed
    asm volatile("s_barrier" ::: "memory");

    for (int t = 0; t < NT; ++t) {
        const int buf = t & 3;
        const int nb = (t + 3) & 3;
        const bool pre = (t + 3 < NT);
        const unsigned short* Ab = Asb + buf * 8192;
        const unsigned short* Bb = Bsb + buf * 6144;

        // ---- phase 1: issue A prefetch, read B + A(lower half), 12 MFMA
        if (pre) stageA(t + 3, nb);
        short8 bfr[3];
#pragma unroll
        for (int j = 0; j < 3; ++j) {
            int r = wn * 48 + j * 16 + lrow;
            bfr[j] = *(const short8*)(Bb + r * 32 +
                                      ((quad ^ ((r >> 1) & 3)) << 3));
        }
        short8 af0[4];
#pragma unroll
        for (int i = 0; i < 4; ++i) {
            int r = wm * 128 + i * 16 + lrow;
            af0[i] = *(const short8*)(Ab + r * 32 +
                                      ((quad ^ ((r >> 1) & 3)) << 3));
        }
        __builtin_amdgcn_s_setprio(1);
#pragma unroll
        for (int i = 0; i < 4; ++i)
#pragma unroll
            for (int j = 0; j < 3; ++j)
                acc[i][j] = __builtin_amdgcn_mfma_f32_16x16x32_bf16(
                    af0[i], bfr[j], acc[i][j], 0, 0, 0);
        __builtin_amdgcn_s_setprio(0);

        // ---- phase 2: issue B prefetch, read A(upper half), 12 MFMA
        if (pre) stageB(t + 3, nb);
        short8 af1[4];
#pragma unroll
        for (int i = 0; i < 4; ++i) {
            int r = wm * 128 + 64 + i * 16 + lrow;
            af1[i] = *(const short8*)(Ab + r * 32 +
                                      ((quad ^ ((r >> 1) & 3)) << 3));
        }
        __builtin_amdgcn_s_setprio(1);
#pragma unroll
        for (int i = 0; i < 4; ++i)
#pragma unroll
            for (int j = 0; j < 3; ++j)
                acc[4 + i][j] = __builtin_amdgcn_mfma_f32_16x16x32_bf16(
                    af1[i], bfr[j], acc[4 + i][j], 0, 0, 0);
        __builtin_amdgcn_s_setprio(0);

        // ---- segment-0 boundary: scale accumulator by router weight w0[m]
        if (t == 31) {
#pragma unroll
            for (int ii = 0; ii < 8; ++ii) {
#pragma unroll
                for (int r = 0; r < 4; ++r) {
                    float f = w0[row0 + wm * 128 + ii * 16 + quad * 4 + r];
#pragma unroll
                    for (int j = 0; j < 3; ++j) acc[ii][j][r] *= f;
                }
            }
        }

        // ---- tile boundary: counted wait (never 0 in steady state) + barrier
        if (t + 1 < NT) {
            if (t + 3 < NT)
                asm volatile("s_waitcnt vmcnt(10)" ::: "memory");
            else if (t + 2 < NT)
                asm volatile("s_waitcnt vmcnt(5)" ::: "memory");
            else
                asm volatile("s_waitcnt vmcnt(0)" ::: "memory");
            asm volatile("s_barrier" ::: "memory");
        }
    }

    // ---- epilogue: weighted-bias add + store
#pragma unroll
    for (int ii = 0; ii < 8; ++ii) {
#pragma unroll
        for (int r = 0; r < 4; ++r) {
            int m = row0 + wm * 128 + ii * 16 + quad * 4 + r;
            float a0 = w0[m], a1 = w1[m], a2 = w2[m];
#pragma unroll
            for (int j = 0; j < 3; ++j) {
                int n = col0 + wn * 48 + j * 16 + lrow;
                C[(size_t)m * ldc + n] =
                    acc[ii][j][r] + a0 * g0[n] + a1 * g1[n] + a2 * g2[n];
            }
        }
    }
}

// BN1 final + relu + bf16 pack.  h1 [8192,512].
__global__ __launch_bounds__(256) void bn_relu_pack(
    const float* __restrict__ h, unsigned short* __restrict__ out,
    const float* __restrict__ sum, const float* __restrict__ sumsq,
    const float* __restrict__ g, const float* __restrict__ b) {
    __shared__ float sc[512], sh[512];
    const float invB = 1.f / 8192.f;
    for (int c = threadIdx.x; c < 512; c += 256) {
        float m = sum[c] * invB;
        float v = sumsq[c] * invB - m * m;
        float s = g[c] * rsqrtf(v + 1e-5f);
        sc[c] = s;
        sh[c] = b[c] - m * s;
    }
    __syncthreads();
    int base = blockIdx.x * 4096;  // vec4 units; 256 blocks
#pragma unroll
    for (int k = 0; k < 16; ++k) {
        int i = base + k * 256 + threadIdx.x;
        int c4 = (i & 127) * 4;
        float4 v = ((const float4*)h)[i];
        ushort4 o;
        o.x = f2bf(fmaxf(v.x * sc[c4 + 0] + sh[c4 + 0], 0.f));
        o.y = f2bf(fmaxf(v.y * sc[c4 + 1] + sh[c4 + 1], 0.f));
        o.z = f2bf(fmaxf(v.z * sc[c4 + 2] + sh[c4 + 2], 0.f));
        o.w = f2bf(fmaxf(v.w * sc[c4 + 3] + sh[c4 + 3], 0.f));
        ((ushort4*)out)[i] = o;
    }
}

// BN2 final + tanh + [100x3] GEMM + sigmoid + softmax.
__global__ __launch_bounds__(128) void router_tail(
    const float* __restrict__ h2, const float* __restrict__ sum,
    const float* __restrict__ sumsq, const float* __restrict__ g,
    const float* __restrict__ b, const float* __restrict__ rw3,
    const float* __restrict__ rb3, float* __restrict__ w0,
    float* __restrict__ w1, float* __restrict__ w2) {
    __shared__ float sc[100], sh[100], w3[300], b3[3];
    int tid = threadIdx.x;
    const float invB = 1.f / 8192.f;
    if (tid < 100) {
        float m = sum[tid] * invB;
        float v = sumsq[tid] * invB - m * m;
        float s = g[tid] * rsqrtf(v + 1e-5f);
        sc[tid] = s;
        sh[tid] = b[tid] - m * s;
    }
    for (int i = tid; i < 300; i += 128) w3[i] = rw3[i];
    if (tid < 3) b3[tid] = rb3[tid];
    __syncthreads();
    int bi = blockIdx.x * 128 + tid;
    float l0 = b3[0], l1 = b3[1], l2 = b3[2];
    const float* hr = h2 + (size_t)bi * 100;
    for (int k = 0; k < 100; ++k) {
        float t = tanhf(hr[k] * sc[k] + sh[k]);
        l0 += t * w3[k * 3 + 0];
        l1 += t * w3[k * 3 + 1];
        l2 += t * w3[k * 3 + 2];
    }
    l0 = 1.f / (1.f + expf(-l0));
    l1 = 1.f / (1.f + expf(-l1));
    l2 = 1.f / (1.f + expf(-l2));
    float mx = fmaxf(l0, fmaxf(l1, l2));
    float e0 = expf(l0 - mx), e1 = expf(l1 - mx), e2 = expf(l2 - mx);
    float inv = 1.f / (e0 + e1 + e2);
    w0[bi] = e0 * inv; w1[bi] = e1 * inv; w2[bi] = e2 * inv;
}

// Pack w1*x1 -> X1b [8192,768] and w2*xib -> Xib [8192,1024] as bf16.
// 448 vec4 groups per row; 3584 blocks x 256 threads x 4 iters (exact).
__global__ __launch_bounds__(256) void pack1ib(
    const float* __restrict__ x1, const float* __restrict__ xib,
    const float* __restrict__ w1, const float* __restrict__ w2,
    unsigned short* __restrict__ X1b, unsigned short* __restrict__ Xib) {
    int i0 = blockIdx.x * 1024 + threadIdx.x;
#pragma unroll
    for (int k = 0; k < 4; ++k) {
        int i = i0 + k * 256;
        int b = i / 448;
        int g = i % 448;
        float w;
        const float* src;
        unsigned short* dst;
        if (g < 192) {
            w = w1[b];
            src = x1 + (size_t)b * 768 + g * 4;
            dst = X1b + (size_t)b * 768 + g * 4;
        } else {
            w = w2[b];
            src = xib + (size_t)b * 1024 + (g - 192) * 4;
            dst = Xib + (size_t)b * 1024 + (g - 192) * 4;
        }
        float4 v = *(const float4*)src;
        ushort4 o;
        o.x = f2bf(v.x * w); o.y = f2bf(v.y * w);
        o.z = f2bf(v.z * w); o.w = f2bf(v.w * w);
        *(ushort4*)dst = o;
    }
}

// per-row L2 normalization in place, one wave per row (1536 cols)
__global__ __launch_bounds__(256) void l2norm_rows(float* __restrict__ out) {
    int wv = threadIdx.x >> 6;
    int lane = threadIdx.x & 63;
    int row = blockIdx.x * 4 + wv;
    float4* rp = (float4*)(out + (size_t)row * 1536);
    float4 v[6];
    float ss = 0.f;
#pragma unroll
    for (int t = 0; t < 6; ++t) {
        v[t] = rp[lane + t * 64];
        ss += v[t].x * v[t].x + v[t].y * v[t].y + v[t].z * v[t].z + v[t].w * v[t].w;
    }
#pragma unroll
    for (int o = 32; o > 0; o >>= 1) ss += __shfl_xor(ss, o);
    float inv = 1.f / fmaxf(sqrtf(ss), 1e-12f);
#pragma unroll
    for (int t = 0; t < 6; ++t) {
        v[t].x *= inv; v[t].y *= inv; v[t].z *= inv; v[t].w *= inv;
        rp[lane + t * 64] = v[t];
    }
}

extern "C" void kernel_launch(void* const* d_in, const int* in_sizes, int n_in,
                              void* d_out, int out_size, void* d_ws,
                              size_t ws_size, hipStream_t stream) {
    (void)in_sizes; (void)n_in; (void)out_size; (void)ws_size;
    const float* x0   = (const float*)d_in[0];
    const float* x1   = (const float*)d_in[1];
    const float* xib  = (const float*)d_in[2];
    const float* pW0  = (const float*)d_in[3];
    const float* pb0  = (const float*)d_in[4];
    const float* pW1  = (const float*)d_in[5];
    const float* pb1  = (const float*)d_in[6];
    const float* pWib = (const float*)d_in[7];
    const float* pbib = (const float*)d_in[8];
    const float* rw1  = (const float*)d_in[9];
    const float* rb1  = (const float*)d_in[10];
    const float* rg1  = (const float*)d_in[11];
    const float* rbt1 = (const float*)d_in[12];
    const float* rw2  = (const float*)d_in[13];
    const float* rb2  = (const float*)d_in[14];
    const float* rg2  = (const float*)d_in[15];
    const float* rbt2 = (const float*)d_in[16];
    const float* rw3  = (const float*)d_in[17];
    const float* rb3  = (const float*)d_in[18];
    float* out = (float*)d_out;

    char* ws = (char*)d_ws;
    // --- workspace layout (~53.5 MB, with temporal aliasing) ---
    unsigned short* Wmt = (unsigned short*)(ws);  // [1536, 2816] bf16
    char* stats = ws + 8650752;
    float* sum1   = (float*)(stats + 0);      // 512 f
    float* sumsq1 = (float*)(stats + 2048);   // 512 f
    float* sum2   = (float*)(stats + 4096);   // 128 f
    float* sumsq2 = (float*)(stats + 4608);   // 128 f  (zero region = 1280 f)
    float* bm0    = (float*)(stats + 10240);
    float* bm1    = (float*)(stats + 16384);
    float* bm2    = (float*)(stats + 22528);
    float* w0p    = (float*)(stats + 28672);
    float* w1p    = (float*)(stats + 61440);
    float* w2p    = (float*)(stats + 94208);
    unsigned short* rw1t = (unsigned short*)(ws + 8781824);   // [512,1024] bf16
    unsigned short* rw2t = (unsigned short*)(ws + 9830400);   // [128,512] bf16 (padded)
    char* R5 = ws + 9961472;
    // Segment-0 A (unscaled x0 bf16), also GEMM1's A.  Lives prep -> gemm256.
    unsigned short* X0b = (unsigned short*)(R5);              // [8192,1024] bf16
    // Router intermediates — dead before X1b/Xib are written (after router_tail)
    float* h1           = (float*)(R5 + 16777216);            // [8192,512] f32
    unsigned short* h1n = (unsigned short*)(R5 + 33554432);   // [8192,512] bf16
    float* h2           = (float*)(R5 + 41943040);            // [8192,100] f32
    // Pre-scaled A segments 1,2 (aliases h1/h1n/h2 region; exact fit)
    unsigned short* X1b = (unsigned short*)(R5 + 16777216);   // [8192,768] bf16
    unsigned short* Xib = (unsigned short*)(R5 + 29360128);   // [8192,1024] bf16

    // 1. fused prep: weight transforms + bias means + x0 pack + stats zero
    prep<<<6855, 256, 0, stream>>>(pW0, pW1, pWib, rw1, rw2, pb0, pb1, pbib, x0,
                                   Wmt, rw1t, rw2t, bm0, bm1, bm2,
                                   (float*)stats, X0b);
    // 2. router GEMM1: h1 = x0 @ rw1 + rb1, with fused BN stats
    gemm_bt<2><<<dim3(64, 4), 256, 0, stream>>>(
        X0b, rw1t, h1, 1024, 512, 512, rb1, sum1, sumsq1);
    // 3. BN1 apply + relu + bf16 pack
    bn_relu_pack<<<256, 256, 0, stream>>>(h1, h1n, sum1, sumsq1, rg1, rbt1);
    // 4. router GEMM2: h2 = h1n @ rw2 + rb2 (N padded to 128), fused BN stats
    gemm_bt<2><<<dim3(64, 1), 256, 0, stream>>>(
        h1n, rw2t, h2, 512, 100, 100, rb2, sum2, sumsq2);
    // 5. BN2 + tanh + small GEMM + sigmoid + softmax -> router weights
    router_tail<<<64, 128, 0, stream>>>(h2, sum2, sumsq2, rg2, rbt2, rw3, rb3,
                                        w0p, w1p, w2p);
    // 6. pack scaled x1/xib segments (h1/h1n/h2 now dead)
    pack1ib<<<3584, 256, 0, stream>>>(x1, xib, w1p, w2p, X1b, Xib);
    // 7. big GEMM + segment-0 weight fold + weighted-bias epilogue
    gemm256<<<dim3(32, 8), 512, 0, stream>>>(X0b, X1b, Xib, Wmt, out, 1536,
                                             w0p, w1p, w2p, bm0, bm1, bm2);
    // 8. per-row L2 normalize
    l2norm_rows<<<2048, 256, 0, stream>>>(out);
}